// Round 10
// baseline (550.443 us; speedup 1.0000x reference)
//
#include <hip/hip_runtime.h>
#include <math.h>

#define NPTS 12288
#define DIM 64
#define KNN 85
#define KSEL 86          // 85 neighbors + self
#define SAMPLE 2000
#define SSTRIDE 6        // deterministic sample: idx = 6*p, p in [0,2000)
#define GAMMA 0.5f
#define NT 256           // block size (4 waves) -- R5/R8 proven no-spill shape
#define WPB 4            // waves per block
#define VIT 12           // float4 dist iterations: 12*256*4 = 12288
#define NV 48            // d2 values per lane; MUST stay fully unrolled (R7)
#define LCAP 128         // per-wave candidate capacity (~88-92 expected)
#define VCAP 96          // block-level valid-neighbor capacity (exactly <=85)
#define PT 32            // pearson tile (32 keeps union LDS < 20 KB)
#define PPITCH 36        // padded LDS pitch (floats), 16B-aligned
#define PGRID 63         // ceil(2000/32)
#define PBLKS (PGRID * PGRID)

// ws layout: [0..36] double accumulators; offset 512: cx[N], cy[N], cz[N]
// acc: [0..4] pearson sums; [5..36] spread slots for local-loss partials

__global__ void prep_kernel(const float* __restrict__ coord,
                            float* __restrict__ cx, float* __restrict__ cy,
                            float* __restrict__ cz) {
  int j = blockIdx.x * 256 + threadIdx.x;
  if (j < NPTS) {
    cx[j] = coord[3 * j];
    cy[j] = coord[3 * j + 1];
    cz[j] = coord[3 * j + 2];
  }
}

// exact wave-local radix select (4x8-bit passes) over NV_ vals/lane; values of
// 0xFFFFFFFF are padding and skipped (safe: pool always holds >= want reals).
// h = wave-private 256-bin LDS histogram (wave-internal DS ordering only).
template <int NV_>
__device__ __forceinline__ unsigned wave_select4(const unsigned v[NV_], unsigned want,
                                                 unsigned* h, int lane) {
  unsigned prefix = 0;
  #pragma unroll
  for (int pass = 0; pass < 4; ++pass) {
    const int shift = 24 - 8 * pass;
    const unsigned hmask = pass ? (0xFFFFFFFFu << (shift + 8)) : 0u;
    h[lane] = 0; h[lane + 64] = 0; h[lane + 128] = 0; h[lane + 192] = 0;
    __builtin_amdgcn_wave_barrier();
    #pragma unroll
    for (int t = 0; t < NV_; ++t) {
      unsigned u = v[t];
      if (u != 0xFFFFFFFFu && (u & hmask) == prefix)
        atomicAdd(&h[(u >> shift) & 255u], 1u);
    }
    __builtin_amdgcn_wave_barrier();
    unsigned c0 = h[4 * lane], c1 = h[4 * lane + 1];
    unsigned c2 = h[4 * lane + 2], c3 = h[4 * lane + 3];
    unsigned lt = c0 + c1 + c2 + c3;
    unsigned incl = lt;
    #pragma unroll
    for (int off = 1; off < 64; off <<= 1) {
      unsigned t2 = __shfl_up(incl, off, 64);
      if (lane >= off) incl += t2;
    }
    unsigned excl = incl - lt;
    bool has = (lt > 0) && (excl < want) && (want <= incl);
    unsigned bin = 4 * lane, below = excl, cum = excl;
    if (cum + c0 >= want) { bin = 4 * lane; below = cum; }
    else { cum += c0;
      if (cum + c1 >= want) { bin = 4 * lane + 1; below = cum; }
      else { cum += c1;
        if (cum + c2 >= want) { bin = 4 * lane + 2; below = cum; }
        else { cum += c2; bin = 4 * lane + 3; below = cum; } } }
    unsigned long long bal = __ballot(has);
    int src = __ffsll((unsigned long long)bal) - 1;
    bin = __shfl(bin, src, 64);
    below = __shfl(below, src, 64);
    prefix |= bin << shift;
    want -= below;
  }
  return prefix;
}

// Fused kernel: blocks [0, NPTS) run the knn/local-loss body; blocks
// [NPTS, NPTS+PBLKS) run the pearson tile body. Block-uniform role switch.
// LDS union ~19.6 KB -> 8 blocks/CU cap; launch_bounds(256,8) requests the
// <=64-VGPR class (8 waves/SIMD). Spill tripwire: WRITE_SIZE must stay ~1.6KB.
__global__ __launch_bounds__(NT, 8) void fused_kernel(
    const float* __restrict__ emb,
    const float* __restrict__ cx, const float* __restrict__ cy,
    const float* __restrict__ cz, double* __restrict__ acc) {
  __shared__ union SM {
    struct {
      unsigned hist[WPB][256];       // 4 KiB
      unsigned nbu[WPB][LCAP];       // 2 KiB
      unsigned short nbj[WPB][LCAP]; // 1 KiB
      unsigned wcnt[WPB];
      unsigned vn_u[VCAP];
      unsigned short vn_j[VCAP];
      unsigned vcnt;
      unsigned selg;
    } k;
    struct {
      float EpT[DIM][PPITCH];        // 9 KiB (transposed tile)
      float EqT[DIM][PPITCH];        // 9 KiB
      float Cp[PT][4];
      float Cq[PT][4];
      double wred[4][5];
    } p;
  } sm;

  const int tid = threadIdx.x;
  const int lane = tid & 63;
  const int wv = tid >> 6;

  if (blockIdx.x < NPTS) {
    // ================= KNN / local-loss body (R8 structure) =================
    const int i = blockIdx.x;

    const float qx = cx[i], qy = cy[i], qz = cz[i];
    const float4* CX4 = (const float4*)cx;
    const float4* CY4 = (const float4*)cy;
    const float4* CZ4 = (const float4*)cz;

    // 48 d2 values per thread in VGPRs. FULL unroll is mandatory: constant
    // indices -> register promotion (R7: unroll 1 => 593 MB scratch spill).
    unsigned d2b[NV];
    #pragma unroll
    for (int it = 0; it < VIT; ++it) {
      int idx = it * NT + tid;
      float4 x4 = CX4[idx], y4 = CY4[idx], z4 = CZ4[idx];
      float dx, dy, dz;
      dx = qx - x4.x; dy = qy - y4.x; dz = qz - z4.x;
      d2b[4 * it + 0] = __float_as_uint(dx * dx + dy * dy + dz * dz);
      dx = qx - x4.y; dy = qy - y4.y; dz = qz - z4.y;
      d2b[4 * it + 1] = __float_as_uint(dx * dx + dy * dy + dz * dz);
      dx = qx - x4.z; dy = qy - y4.z; dz = qz - z4.z;
      d2b[4 * it + 2] = __float_as_uint(dx * dx + dy * dy + dz * dz);
      dx = qx - x4.w; dy = qy - y4.w; dz = qz - z4.w;
      d2b[4 * it + 3] = __float_as_uint(dx * dx + dy * dy + dz * dz);
    }

    // ---- VALU pre-filter: per-lane two smallest (uint order == float order) --
    unsigned m1 = 0xFFFFFFFFu, m2 = 0xFFFFFFFFu;
    #pragma unroll
    for (int t = 0; t < NV; ++t) {
      unsigned u = d2b[t];
      unsigned hi = u > m1 ? u : m1;
      m1 = u < m1 ? u : m1;
      m2 = hi < m2 ? hi : m2;
    }
    // M2 = wave-max of 2nd-smallest: >=128 values <= M2, so wave-86th <= M2
    unsigned M2 = m2;
    #pragma unroll
    for (int off = 32; off > 0; off >>= 1) {
      unsigned t2 = __shfl_xor((int)M2, off, 64);
      M2 = t2 > M2 ? t2 : M2;
    }
    const float M2f = __uint_as_float(M2);
    const float sbin = 256.0f / fmaxf(M2f, 1e-30f);

    // ---- single linear-binned histogram over filtered values ----
    unsigned* h = sm.k.hist[wv];
    h[lane] = 0; h[lane + 64] = 0; h[lane + 128] = 0; h[lane + 192] = 0;
    __builtin_amdgcn_wave_barrier();
    #pragma unroll
    for (int t = 0; t < NV; ++t) {
      unsigned u = d2b[t];
      if (u <= M2) {
        int b = (int)(__uint_as_float(u) * sbin);
        b = b > 255 ? 255 : b;
        atomicAdd(&h[b], 1u);
      }
    }
    __builtin_amdgcn_wave_barrier();
    unsigned c0 = h[4 * lane], c1 = h[4 * lane + 1];
    unsigned c2 = h[4 * lane + 2], c3 = h[4 * lane + 3];
    unsigned lt = c0 + c1 + c2 + c3;
    unsigned incl = lt;
    #pragma unroll
    for (int off = 1; off < 64; off <<= 1) {
      unsigned t2 = __shfl_up(incl, off, 64);
      if (lane >= off) incl += t2;
    }
    unsigned excl = incl - lt;
    bool has = (lt > 0) && (excl < KSEL) && (KSEL <= incl);
    unsigned bin = 4 * lane, cum = excl;
    if (cum + c0 >= KSEL) { bin = 4 * lane; }
    else { cum += c0;
      if (cum + c1 >= KSEL) { bin = 4 * lane + 1; }
      else { cum += c1;
        if (cum + c2 >= KSEL) { bin = 4 * lane + 2; }
        else { bin = 4 * lane + 3; } } }
    unsigned long long bal = __ballot(has);
    int src = __ffsll((unsigned long long)bal) - 1;
    unsigned bsel = __shfl((int)bin, src, 64);
    // inclusive upper edge of the selected bucket (2-ulp safety margin up)
    float Uf = (float)(bsel + 1) * (M2f * (1.0f / 256.0f)) * 1.000002f;
    unsigned U = __float_as_uint(Uf);

    // ---- guarded atomic append of candidates u <= U (~88-92 per wave) ----
    if (lane == 0) sm.k.wcnt[wv] = 0;
    if (tid == 0) sm.k.vcnt = 0;
    __builtin_amdgcn_wave_barrier();
    #pragma unroll
    for (int t = 0; t < NV; ++t) {
      unsigned u = d2b[t];
      if (u <= U) {
        unsigned pos = atomicAdd(&sm.k.wcnt[wv], 1u);
        if (pos < LCAP) {
          sm.k.nbu[wv][pos] = u;
          int it = t >> 2, c = t & 3;
          sm.k.nbj[wv][pos] = (unsigned short)(4 * (it * NT + tid) + c);
        }
      }
    }
    __syncthreads();   // barrier 1: lists + vcnt=0 visible

    // ---- wave 0 only: exact global 86th among the union (R9 lesson: the
    // redundant all-wave merge quadruples LDS conflicts for zero gain) ----
    if (wv == 0) {
      unsigned mv[2 * WPB];
      #pragma unroll
      for (int w = 0; w < WPB; ++w) {
        unsigned mw = sm.k.wcnt[w] < LCAP ? sm.k.wcnt[w] : LCAP;
        mv[2 * w]     = ((unsigned)lane < mw)      ? sm.k.nbu[w][lane]      : 0xFFFFFFFFu;
        mv[2 * w + 1] = ((unsigned)lane + 64 < mw) ? sm.k.nbu[w][lane + 64] : 0xFFFFFFFFu;
      }
      unsigned t = wave_select4<2 * WPB>(mv, KSEL, sm.k.hist[0], lane);
      if (lane == 0) sm.k.selg = t;
    }
    __syncthreads();   // barrier 2: threshold visible
    const unsigned thrg = sm.k.selg;

    // ---- compact the true 85 neighbors into one block-level list ----
    const int mw = (int)(sm.k.wcnt[wv] < LCAP ? sm.k.wcnt[wv] : LCAP);
    for (int n = lane; n < mw; n += 64) {
      unsigned u = sm.k.nbu[wv][n];
      int j = (int)sm.k.nbj[wv][n];
      if (u <= thrg && j != i) {
        unsigned p = atomicAdd(&sm.k.vcnt, 1u);
        if (p < VCAP) { sm.k.vn_u[p] = u; sm.k.vn_j[p] = (unsigned short)j; }
      }
    }
    __syncthreads();   // barrier 3: valid list visible
    const int tot = (int)(sm.k.vcnt < VCAP ? sm.k.vcnt : VCAP);

    // ---- loss: 16 neighbors per block-iteration (4 waves x 4 quarters) ----
    // ei4 loaded HERE (deferred: keeps it out of the dist-phase live set)
    const int q = lane >> 4;
    const int l16 = lane & 15;
    const float4 ei4 = ((const float4*)(emb + (size_t)i * DIM))[l16];
    float lsum = 0.f;
    for (int base = wv * 4; base < tot; base += 16) {  // wave-uniform trips
      int idx = base + q;
      bool valid = idx < tot;
      unsigned u = 0; int j = 0;
      if (valid) { u = sm.k.vn_u[idx]; j = (int)sm.k.vn_j[idx]; }
      float s = 0.f;
      if (valid) {
        float4 e4 = ((const float4*)(emb + (size_t)j * DIM))[l16];
        float d0 = ei4.x - e4.x, d1 = ei4.y - e4.y;
        float d2 = ei4.z - e4.z, d3 = ei4.w - e4.w;
        s = d0 * d0 + d1 * d1 + d2 * d2 + d3 * d3;
      }
      s += __shfl_xor(s, 1, 64);
      s += __shfl_xor(s, 2, 64);
      s += __shfl_xor(s, 4, 64);
      s += __shfl_xor(s, 8, 64);
      if (valid && l16 == 0) {
        float td = sqrtf(__uint_as_float(u));
        float pd = sqrtf(fmaxf(s, 0.f));
        float diff = pd - td;
        lsum += diff * diff * expf(-GAMMA * td);
      }
    }
    #pragma unroll
    for (int off = 32; off > 0; off >>= 1) lsum += __shfl_xor(lsum, off, 64);
    if (lane == 0) atomicAdd(&acc[5 + (blockIdx.x & 7) * 4 + wv], (double)lsum);

  } else {
    // ================= Pearson tile body (32x32, 2x2 blocking) ==============
    const int bid = blockIdx.x - NPTS;
    const int tx = tid & 15, ty = tid >> 4;
    const int p0 = (bid / PGRID) * PT, q0 = (bid % PGRID) * PT;

    for (int e = tid; e < PT * DIM; e += 256) {
      int r = e >> 6, k = e & 63;
      int gp = (p0 + r < SAMPLE ? p0 + r : 0) * SSTRIDE;
      int gq = (q0 + r < SAMPLE ? q0 + r : 0) * SSTRIDE;
      sm.p.EpT[k][r] = emb[(size_t)gp * DIM + k];
      sm.p.EqT[k][r] = emb[(size_t)gq * DIM + k];
    }
    if (tid < PT) {
      int g = (p0 + tid < SAMPLE ? p0 + tid : 0) * SSTRIDE;
      sm.p.Cp[tid][0] = cx[g]; sm.p.Cp[tid][1] = cy[g]; sm.p.Cp[tid][2] = cz[g];
    } else if (tid < 2 * PT) {
      int r = tid - PT;
      int g = (q0 + r < SAMPLE ? q0 + r : 0) * SSTRIDE;
      sm.p.Cq[r][0] = cx[g]; sm.p.Cq[r][1] = cy[g]; sm.p.Cq[r][2] = cz[g];
    }
    __syncthreads();

    float s[2][2] = {};
    #pragma unroll 8
    for (int k = 0; k < DIM; ++k) {
      float2 ep = *(const float2*)&sm.p.EpT[k][2 * ty];
      float2 eq = *(const float2*)&sm.p.EqT[k][2 * tx];
      float d;
      d = ep.x - eq.x; s[0][0] += d * d;
      d = ep.x - eq.y; s[0][1] += d * d;
      d = ep.y - eq.x; s[1][0] += d * d;
      d = ep.y - eq.y; s[1][1] += d * d;
    }

    double se = 0, sc = 0, se2 = 0, sc2 = 0, sec = 0;
    #pragma unroll
    for (int a = 0; a < 2; ++a)
      #pragma unroll
      for (int b = 0; b < 2; ++b) {
        int p = p0 + 2 * ty + a, q = q0 + 2 * tx + b;
        if (p < SAMPLE && q < SAMPLE) {
          float ed = sqrtf(fmaxf(s[a][b], 0.f));
          float dx = sm.p.Cp[2 * ty + a][0] - sm.p.Cq[2 * tx + b][0];
          float dy = sm.p.Cp[2 * ty + a][1] - sm.p.Cq[2 * tx + b][1];
          float dz = sm.p.Cp[2 * ty + a][2] - sm.p.Cq[2 * tx + b][2];
          float cd = sqrtf(fmaxf(dx * dx + dy * dy + dz * dz, 0.f));
          se += (double)ed; sc += (double)cd;
          se2 += (double)ed * ed; sc2 += (double)cd * cd;
          sec += (double)ed * cd;
        }
      }

    double vals[5] = { se, sc, se2, sc2, sec };
    #pragma unroll
    for (int v = 0; v < 5; ++v) {
      #pragma unroll
      for (int off = 32; off > 0; off >>= 1) vals[v] += __shfl_xor(vals[v], off, 64);
    }
    if (lane == 0) {
      #pragma unroll
      for (int v = 0; v < 5; ++v) sm.p.wred[wv][v] = vals[v];
    }
    __syncthreads();
    if (tid < 5) {
      double smv = sm.p.wred[0][tid] + sm.p.wred[1][tid] + sm.p.wred[2][tid] +
                   sm.p.wred[3][tid];
      atomicAdd(&acc[tid], smv);
    }
  }
}

__global__ void finalize_kernel(const double* __restrict__ acc,
                                float* __restrict__ out) {
  double M = (double)SAMPLE * (double)SAMPLE;
  double med = acc[0] / M, mcd = acc[1] / M;
  double ve = acc[2] / M - med * med;
  double vc = acc[3] / M - mcd * mcd;
  double es = sqrt(ve + 1e-8);
  double cs = sqrt(vc + 1e-8);
  double cov = acc[4] / M - med * mcd;
  double pearson = cov / (es * cs + 1e-8);
  double lsum = 0.0;
  for (int s = 5; s < 37; ++s) lsum += acc[s];
  double local = lsum / ((double)NPTS * (double)KNN);
  out[0] = (float)((1.0 - pearson) + 0.5 * local);
}

extern "C" void kernel_launch(void* const* d_in, const int* in_sizes, int n_in,
                              void* d_out, int out_size, void* d_ws, size_t ws_size,
                              hipStream_t stream) {
  const float* emb = (const float*)d_in[0];    // (12288, 64) f32
  const float* coord = (const float*)d_in[1];  // (12288, 3) f32
  double* acc = (double*)d_ws;
  float* cx = (float*)((char*)d_ws + 512);     // 16B-aligned SoA coords
  float* cy = cx + NPTS;
  float* cz = cy + NPTS;

  hipMemsetAsync(d_ws, 0, 37 * sizeof(double), stream);

  prep_kernel<<<(NPTS + 255) / 256, 256, 0, stream>>>(coord, cx, cy, cz);

  fused_kernel<<<NPTS + PBLKS, NT, 0, stream>>>(emb, cx, cy, cz, acc);

  finalize_kernel<<<1, 1, 0, stream>>>(acc, (float*)d_out);
}

// Round 11
// 368.200 us; speedup vs baseline: 1.4950x; 1.4950x over previous
//
#include <hip/hip_runtime.h>
#include <math.h>

#define NPTS 12288
#define DIM 64
#define KNN 85
#define KSEL 86          // 85 neighbors + self
#define SAMPLE 2000
#define SSTRIDE 6        // deterministic sample: idx = 6*p, p in [0,2000)
#define GAMMA 0.5f
#define NT 256           // block size (4 waves) -- R5/R8 proven no-spill shape
#define WPB 4            // waves per block
#define VIT 12           // float4 dist iterations: 12*256*4 = 12288
#define NV 48            // d2 values per lane; MUST stay fully unrolled (R7)
#define LCAP 128         // per-wave candidate capacity (~88-92 expected)
#define VCAP 96          // block-level valid-neighbor capacity (exactly <=85)
#define PT 32            // pearson tile (32x32, union LDS < 20 KB)
#define PPITCH 36        // padded LDS pitch (floats), 16B-aligned
#define PGRID 63         // ceil(2000/32)
#define PBLKS (PGRID * PGRID)

// ws layout: [0..36] double accumulators; offset 512: cx[N], cy[N], cz[N]
// acc: [0..4] pearson sums; [5..36] spread slots for local-loss partials

__global__ void prep_kernel(const float* __restrict__ coord,
                            float* __restrict__ cx, float* __restrict__ cy,
                            float* __restrict__ cz) {
  int j = blockIdx.x * 256 + threadIdx.x;
  if (j < NPTS) {
    cx[j] = coord[3 * j];
    cy[j] = coord[3 * j + 1];
    cz[j] = coord[3 * j + 2];
  }
}

// exact wave-local radix select (4x8-bit passes) over NV_ vals/lane; values of
// 0xFFFFFFFF are padding and skipped (safe: pool always holds >= want reals).
// h = wave-private 256-bin LDS histogram (wave-internal DS ordering only).
template <int NV_>
__device__ __forceinline__ unsigned wave_select4(const unsigned v[NV_], unsigned want,
                                                 unsigned* h, int lane) {
  unsigned prefix = 0;
  #pragma unroll
  for (int pass = 0; pass < 4; ++pass) {
    const int shift = 24 - 8 * pass;
    const unsigned hmask = pass ? (0xFFFFFFFFu << (shift + 8)) : 0u;
    h[lane] = 0; h[lane + 64] = 0; h[lane + 128] = 0; h[lane + 192] = 0;
    __builtin_amdgcn_wave_barrier();
    #pragma unroll
    for (int t = 0; t < NV_; ++t) {
      unsigned u = v[t];
      if (u != 0xFFFFFFFFu && (u & hmask) == prefix)
        atomicAdd(&h[(u >> shift) & 255u], 1u);
    }
    __builtin_amdgcn_wave_barrier();
    unsigned c0 = h[4 * lane], c1 = h[4 * lane + 1];
    unsigned c2 = h[4 * lane + 2], c3 = h[4 * lane + 3];
    unsigned lt = c0 + c1 + c2 + c3;
    unsigned incl = lt;
    #pragma unroll
    for (int off = 1; off < 64; off <<= 1) {
      unsigned t2 = __shfl_up(incl, off, 64);
      if (lane >= off) incl += t2;
    }
    unsigned excl = incl - lt;
    bool has = (lt > 0) && (excl < want) && (want <= incl);
    unsigned bin = 4 * lane, below = excl, cum = excl;
    if (cum + c0 >= want) { bin = 4 * lane; below = cum; }
    else { cum += c0;
      if (cum + c1 >= want) { bin = 4 * lane + 1; below = cum; }
      else { cum += c1;
        if (cum + c2 >= want) { bin = 4 * lane + 2; below = cum; }
        else { cum += c2; bin = 4 * lane + 3; below = cum; } } }
    unsigned long long bal = __ballot(has);
    int src = __ffsll((unsigned long long)bal) - 1;
    bin = __shfl(bin, src, 64);
    below = __shfl(below, src, 64);
    prefix |= bin << shift;
    want -= below;
  }
  return prefix;
}

// Fused kernel: blocks [0, NPTS) run the knn/local-loss body; blocks
// [NPTS, NPTS+PBLKS) run the pearson tile body. Block-uniform role switch.
// NO min-waves launch bound: d2b[48]'s live set is ~80 VGPR; any cap <=64
// spills catastrophically (R6/R10: 0.6-2 GB of scratch traffic).
__global__ __launch_bounds__(NT) void fused_kernel(
    const float* __restrict__ emb,
    const float* __restrict__ cx, const float* __restrict__ cy,
    const float* __restrict__ cz, double* __restrict__ acc) {
  __shared__ union SM {
    struct {
      unsigned hist[WPB][256];       // 4 KiB
      unsigned nbu[WPB][LCAP];       // 2 KiB
      unsigned short nbj[WPB][LCAP]; // 1 KiB
      unsigned wcnt[WPB];
      unsigned vn_u[VCAP];
      unsigned short vn_j[VCAP];
      unsigned vcnt;
      unsigned selg;
    } k;
    struct {
      float EpT[DIM][PPITCH];        // 9 KiB (transposed tile)
      float EqT[DIM][PPITCH];        // 9 KiB
      float Cp[PT][4];
      float Cq[PT][4];
      double wred[4][5];
    } p;
  } sm;

  const int tid = threadIdx.x;
  const int lane = tid & 63;
  const int wv = tid >> 6;

  if (blockIdx.x < NPTS) {
    // ================= KNN / local-loss body (R8 structure) =================
    const int i = blockIdx.x;

    const float qx = cx[i], qy = cy[i], qz = cz[i];
    const float4* CX4 = (const float4*)cx;
    const float4* CY4 = (const float4*)cy;
    const float4* CZ4 = (const float4*)cz;

    // 48 d2 values per thread in VGPRs. FULL unroll is mandatory: constant
    // indices -> register promotion (R7: unroll 1 => 593 MB scratch spill).
    unsigned d2b[NV];
    #pragma unroll
    for (int it = 0; it < VIT; ++it) {
      int idx = it * NT + tid;
      float4 x4 = CX4[idx], y4 = CY4[idx], z4 = CZ4[idx];
      float dx, dy, dz;
      dx = qx - x4.x; dy = qy - y4.x; dz = qz - z4.x;
      d2b[4 * it + 0] = __float_as_uint(dx * dx + dy * dy + dz * dz);
      dx = qx - x4.y; dy = qy - y4.y; dz = qz - z4.y;
      d2b[4 * it + 1] = __float_as_uint(dx * dx + dy * dy + dz * dz);
      dx = qx - x4.z; dy = qy - y4.z; dz = qz - z4.z;
      d2b[4 * it + 2] = __float_as_uint(dx * dx + dy * dy + dz * dz);
      dx = qx - x4.w; dy = qy - y4.w; dz = qz - z4.w;
      d2b[4 * it + 3] = __float_as_uint(dx * dx + dy * dy + dz * dz);
    }

    // ---- VALU pre-filter: per-lane two smallest (uint order == float order) --
    unsigned m1 = 0xFFFFFFFFu, m2 = 0xFFFFFFFFu;
    #pragma unroll
    for (int t = 0; t < NV; ++t) {
      unsigned u = d2b[t];
      unsigned hi = u > m1 ? u : m1;
      m1 = u < m1 ? u : m1;
      m2 = hi < m2 ? hi : m2;
    }
    // M2 = wave-max of 2nd-smallest: >=128 values <= M2, so wave-86th <= M2
    unsigned M2 = m2;
    #pragma unroll
    for (int off = 32; off > 0; off >>= 1) {
      unsigned t2 = __shfl_xor((int)M2, off, 64);
      M2 = t2 > M2 ? t2 : M2;
    }
    const float M2f = __uint_as_float(M2);
    const float sbin = 256.0f / fmaxf(M2f, 1e-30f);

    // ---- single linear-binned histogram over filtered values ----
    unsigned* h = sm.k.hist[wv];
    h[lane] = 0; h[lane + 64] = 0; h[lane + 128] = 0; h[lane + 192] = 0;
    __builtin_amdgcn_wave_barrier();
    #pragma unroll
    for (int t = 0; t < NV; ++t) {
      unsigned u = d2b[t];
      if (u <= M2) {
        int b = (int)(__uint_as_float(u) * sbin);
        b = b > 255 ? 255 : b;
        atomicAdd(&h[b], 1u);
      }
    }
    __builtin_amdgcn_wave_barrier();
    unsigned c0 = h[4 * lane], c1 = h[4 * lane + 1];
    unsigned c2 = h[4 * lane + 2], c3 = h[4 * lane + 3];
    unsigned lt = c0 + c1 + c2 + c3;
    unsigned incl = lt;
    #pragma unroll
    for (int off = 1; off < 64; off <<= 1) {
      unsigned t2 = __shfl_up(incl, off, 64);
      if (lane >= off) incl += t2;
    }
    unsigned excl = incl - lt;
    bool has = (lt > 0) && (excl < KSEL) && (KSEL <= incl);
    unsigned bin = 4 * lane, cum = excl;
    if (cum + c0 >= KSEL) { bin = 4 * lane; }
    else { cum += c0;
      if (cum + c1 >= KSEL) { bin = 4 * lane + 1; }
      else { cum += c1;
        if (cum + c2 >= KSEL) { bin = 4 * lane + 2; }
        else { bin = 4 * lane + 3; } } }
    unsigned long long bal = __ballot(has);
    int src = __ffsll((unsigned long long)bal) - 1;
    unsigned bsel = __shfl((int)bin, src, 64);
    // inclusive upper edge of the selected bucket (2-ulp safety margin up)
    float Uf = (float)(bsel + 1) * (M2f * (1.0f / 256.0f)) * 1.000002f;
    unsigned U = __float_as_uint(Uf);

    // ---- guarded atomic append of candidates u <= U (~88-92 per wave) ----
    if (lane == 0) sm.k.wcnt[wv] = 0;
    if (tid == 0) sm.k.vcnt = 0;
    __builtin_amdgcn_wave_barrier();
    #pragma unroll
    for (int t = 0; t < NV; ++t) {
      unsigned u = d2b[t];
      if (u <= U) {
        unsigned pos = atomicAdd(&sm.k.wcnt[wv], 1u);
        if (pos < LCAP) {
          sm.k.nbu[wv][pos] = u;
          int it = t >> 2, c = t & 3;
          sm.k.nbj[wv][pos] = (unsigned short)(4 * (it * NT + tid) + c);
        }
      }
    }
    __syncthreads();   // barrier 1: lists + vcnt=0 visible

    // ---- wave 0 only: exact global 86th among the union (R9 lesson: the
    // redundant all-wave merge quadruples LDS conflicts, +25 us) ----
    if (wv == 0) {
      unsigned mv[2 * WPB];
      #pragma unroll
      for (int w = 0; w < WPB; ++w) {
        unsigned mw = sm.k.wcnt[w] < LCAP ? sm.k.wcnt[w] : LCAP;
        mv[2 * w]     = ((unsigned)lane < mw)      ? sm.k.nbu[w][lane]      : 0xFFFFFFFFu;
        mv[2 * w + 1] = ((unsigned)lane + 64 < mw) ? sm.k.nbu[w][lane + 64] : 0xFFFFFFFFu;
      }
      unsigned t = wave_select4<2 * WPB>(mv, KSEL, sm.k.hist[0], lane);
      if (lane == 0) sm.k.selg = t;
    }
    __syncthreads();   // barrier 2: threshold visible
    const unsigned thrg = sm.k.selg;

    // ---- compact the true 85 neighbors into one block-level list ----
    const int mw = (int)(sm.k.wcnt[wv] < LCAP ? sm.k.wcnt[wv] : LCAP);
    for (int n = lane; n < mw; n += 64) {
      unsigned u = sm.k.nbu[wv][n];
      int j = (int)sm.k.nbj[wv][n];
      if (u <= thrg && j != i) {
        unsigned p = atomicAdd(&sm.k.vcnt, 1u);
        if (p < VCAP) { sm.k.vn_u[p] = u; sm.k.vn_j[p] = (unsigned short)j; }
      }
    }
    __syncthreads();   // barrier 3: valid list visible
    const int tot = (int)(sm.k.vcnt < VCAP ? sm.k.vcnt : VCAP);

    // ---- loss: 16 neighbors per block-iteration (4 waves x 4 quarters) ----
    const int q = lane >> 4;
    const int l16 = lane & 15;
    const float4 ei4 = ((const float4*)(emb + (size_t)i * DIM))[l16];
    float lsum = 0.f;
    for (int base = wv * 4; base < tot; base += 16) {  // wave-uniform trips
      int idx = base + q;
      bool valid = idx < tot;
      unsigned u = 0; int j = 0;
      if (valid) { u = sm.k.vn_u[idx]; j = (int)sm.k.vn_j[idx]; }
      float s = 0.f;
      if (valid) {
        float4 e4 = ((const float4*)(emb + (size_t)j * DIM))[l16];
        float d0 = ei4.x - e4.x, d1 = ei4.y - e4.y;
        float d2 = ei4.z - e4.z, d3 = ei4.w - e4.w;
        s = d0 * d0 + d1 * d1 + d2 * d2 + d3 * d3;
      }
      s += __shfl_xor(s, 1, 64);
      s += __shfl_xor(s, 2, 64);
      s += __shfl_xor(s, 4, 64);
      s += __shfl_xor(s, 8, 64);
      if (valid && l16 == 0) {
        float td = sqrtf(__uint_as_float(u));
        float pd = sqrtf(fmaxf(s, 0.f));
        float diff = pd - td;
        lsum += diff * diff * expf(-GAMMA * td);
      }
    }
    #pragma unroll
    for (int off = 32; off > 0; off >>= 1) lsum += __shfl_xor(lsum, off, 64);
    if (lane == 0) atomicAdd(&acc[5 + (blockIdx.x & 7) * 4 + wv], (double)lsum);

  } else {
    // ================= Pearson tile body (32x32, 2x2 blocking) ==============
    const int bid = blockIdx.x - NPTS;
    const int tx = tid & 15, ty = tid >> 4;
    const int p0 = (bid / PGRID) * PT, q0 = (bid % PGRID) * PT;

    for (int e = tid; e < PT * DIM; e += 256) {
      int r = e >> 6, k = e & 63;
      int gp = (p0 + r < SAMPLE ? p0 + r : 0) * SSTRIDE;
      int gq = (q0 + r < SAMPLE ? q0 + r : 0) * SSTRIDE;
      sm.p.EpT[k][r] = emb[(size_t)gp * DIM + k];
      sm.p.EqT[k][r] = emb[(size_t)gq * DIM + k];
    }
    if (tid < PT) {
      int g = (p0 + tid < SAMPLE ? p0 + tid : 0) * SSTRIDE;
      sm.p.Cp[tid][0] = cx[g]; sm.p.Cp[tid][1] = cy[g]; sm.p.Cp[tid][2] = cz[g];
    } else if (tid < 2 * PT) {
      int r = tid - PT;
      int g = (q0 + r < SAMPLE ? q0 + r : 0) * SSTRIDE;
      sm.p.Cq[r][0] = cx[g]; sm.p.Cq[r][1] = cy[g]; sm.p.Cq[r][2] = cz[g];
    }
    __syncthreads();

    float s[2][2] = {};
    #pragma unroll 8
    for (int k = 0; k < DIM; ++k) {
      float2 ep = *(const float2*)&sm.p.EpT[k][2 * ty];
      float2 eq = *(const float2*)&sm.p.EqT[k][2 * tx];
      float d;
      d = ep.x - eq.x; s[0][0] += d * d;
      d = ep.x - eq.y; s[0][1] += d * d;
      d = ep.y - eq.x; s[1][0] += d * d;
      d = ep.y - eq.y; s[1][1] += d * d;
    }

    double se = 0, sc = 0, se2 = 0, sc2 = 0, sec = 0;
    #pragma unroll
    for (int a = 0; a < 2; ++a)
      #pragma unroll
      for (int b = 0; b < 2; ++b) {
        int p = p0 + 2 * ty + a, q = q0 + 2 * tx + b;
        if (p < SAMPLE && q < SAMPLE) {
          float ed = sqrtf(fmaxf(s[a][b], 0.f));
          float dx = sm.p.Cp[2 * ty + a][0] - sm.p.Cq[2 * tx + b][0];
          float dy = sm.p.Cp[2 * ty + a][1] - sm.p.Cq[2 * tx + b][1];
          float dz = sm.p.Cp[2 * ty + a][2] - sm.p.Cq[2 * tx + b][2];
          float cd = sqrtf(fmaxf(dx * dx + dy * dy + dz * dz, 0.f));
          se += (double)ed; sc += (double)cd;
          se2 += (double)ed * ed; sc2 += (double)cd * cd;
          sec += (double)ed * cd;
        }
      }

    double vals[5] = { se, sc, se2, sc2, sec };
    #pragma unroll
    for (int v = 0; v < 5; ++v) {
      #pragma unroll
      for (int off = 32; off > 0; off >>= 1) vals[v] += __shfl_xor(vals[v], off, 64);
    }
    if (lane == 0) {
      #pragma unroll
      for (int v = 0; v < 5; ++v) sm.p.wred[wv][v] = vals[v];
    }
    __syncthreads();
    if (tid < 5) {
      double smv = sm.p.wred[0][tid] + sm.p.wred[1][tid] + sm.p.wred[2][tid] +
                   sm.p.wred[3][tid];
      atomicAdd(&acc[tid], smv);
    }
  }
}

__global__ void finalize_kernel(const double* __restrict__ acc,
                                float* __restrict__ out) {
  double M = (double)SAMPLE * (double)SAMPLE;
  double med = acc[0] / M, mcd = acc[1] / M;
  double ve = acc[2] / M - med * med;
  double vc = acc[3] / M - mcd * mcd;
  double es = sqrt(ve + 1e-8);
  double cs = sqrt(vc + 1e-8);
  double cov = acc[4] / M - med * mcd;
  double pearson = cov / (es * cs + 1e-8);
  double lsum = 0.0;
  for (int s = 5; s < 37; ++s) lsum += acc[s];
  double local = lsum / ((double)NPTS * (double)KNN);
  out[0] = (float)((1.0 - pearson) + 0.5 * local);
}

extern "C" void kernel_launch(void* const* d_in, const int* in_sizes, int n_in,
                              void* d_out, int out_size, void* d_ws, size_t ws_size,
                              hipStream_t stream) {
  const float* emb = (const float*)d_in[0];    // (12288, 64) f32
  const float* coord = (const float*)d_in[1];  // (12288, 3) f32
  double* acc = (double*)d_ws;
  float* cx = (float*)((char*)d_ws + 512);     // 16B-aligned SoA coords
  float* cy = cx + NPTS;
  float* cz = cy + NPTS;

  hipMemsetAsync(d_ws, 0, 37 * sizeof(double), stream);

  prep_kernel<<<(NPTS + 255) / 256, 256, 0, stream>>>(coord, cx, cy, cz);

  fused_kernel<<<NPTS + PBLKS, NT, 0, stream>>>(emb, cx, cy, cz, acc);

  finalize_kernel<<<1, 1, 0, stream>>>(acc, (float*)d_out);
}